// Round 22
// baseline (2291.071 us; speedup 1.0000x reference)
//
#include <hip/hip_runtime.h>
#include <hip/hip_bf16.h>
#include <math.h>

// Shapes: B=256, T=1024, F=128, D=256, UNITS=64. Inputs f32; out f32 [B,T,D].
//
// FROZEN arithmetic (r17+, absmax=0.0 bit-exact): sequential ascending-k fmaf
// chains, u=(mm1+mm2)+bias, z=fmaf(sh,u,h1), XLA EmitFastTanh.
// r21 post-mortem: VALU-issue-bound (84.8% busy, 2880 cyc/step): 256 RL +
// ~150 accvgpr moves + RL->FMA SGPR hazards rival the 256-FMA chain itself.
// r22: split multiplier delivery across ports — elements 0..127 via 32
// ds_read_b128 broadcasts (8-deep rolling window, LDS pipe, latency hidden),
// elements 128..255 via readlane groups (VALU). Same chain order, bit-exact.

__device__ __forceinline__ float xla_tanh(float x) {
    const float kClamp = 7.99881172180175781f;
    float xc = fminf(fmaxf(x, -kClamp), kClamp);
    float x2 = xc * xc;
    float num = -2.76076847742355e-16f;
    num = fmaf(x2, num, 2.00018790482477e-13f);
    num = fmaf(x2, num, -8.60467152213735e-11f);
    num = fmaf(x2, num, 5.12229709037114e-08f);
    num = fmaf(x2, num, 1.48572235717979e-05f);
    num = fmaf(x2, num, 6.37261928875436e-04f);
    num = fmaf(x2, num, 4.89352455891786e-03f);
    num = xc * num;
    float den = 1.19825839466702e-06f;
    den = fmaf(x2, den, 1.18534705686654e-04f);
    den = fmaf(x2, den, 2.26843463243900e-03f);
    den = fmaf(x2, den, 4.89352518554385e-03f);
    return (fabsf(x) < 0.0004f) ? x : (num / den);
}

// ---------------- Phase 1: mm1[b,t,d] = dx_t @ K[:,d] (raw, no bias) -------
__global__ __launch_bounds__(256, 2)
void lrs_mm1(const float* __restrict__ x, const float* __restrict__ K,
             float* __restrict__ out) {
    const int d = threadIdx.x;
    float kc[128];
#pragma unroll
    for (int j = 0; j < 128; ++j) kc[j] = K[j * 256 + d];

    __shared__ __align__(16) float dx2[2][128];
    const int m0 = blockIdx.x * 256;          // grid 1024, 256 rows/block
    for (int mm = m0; mm < m0 + 256; mm += 2) {
        __syncthreads();                      // protect dx2 reuse
        if (d < 128) {                        // stage row mm
            const float xa  = x[(size_t)mm * 128 + d];
            const float xpa = (mm & 1023) ? x[(size_t)(mm - 1) * 128 + d] : 0.0f;
            dx2[0][d] = xa - xpa;             // f32 sub (= ref)
        } else {                              // stage row mm+1
            const int dd = d - 128;
            const float xb  = x[(size_t)(mm + 1) * 128 + dd];
            const float xpb = ((mm + 1) & 1023) ? x[(size_t)mm * 128 + dd] : 0.0f;
            dx2[1][dd] = xb - xpb;
        }
        __syncthreads();

        float a0 = 0.0f, a1 = 0.0f;
#pragma unroll
        for (int j = 0; j < 128; j += 4) {
            const float4 v0 = *reinterpret_cast<const float4*>(&dx2[0][j]);
            const float4 v1 = *reinterpret_cast<const float4*>(&dx2[1][j]);
            a0 = fmaf(v0.x, kc[j + 0], a0);  a1 = fmaf(v1.x, kc[j + 0], a1);
            a0 = fmaf(v0.y, kc[j + 1], a0);  a1 = fmaf(v1.y, kc[j + 1], a1);
            a0 = fmaf(v0.z, kc[j + 2], a0);  a1 = fmaf(v1.z, kc[j + 2], a1);
            a0 = fmaf(v0.w, kc[j + 3], a0);  a1 = fmaf(v1.w, kc[j + 3], a1);
        }
        out[(size_t)mm * 256 + d]       = a0;
        out[(size_t)(mm + 1) * 256 + d] = a1;
    }
}

// ---------------- Phase 2: recurrence ---------------------------------------
__device__ __forceinline__ float rdlane(float v, int l) {
    return __uint_as_float(__builtin_amdgcn_readlane(__float_as_uint(v), l));
}

__global__ __launch_bounds__(256, 1)
void lrs_rec(const float* __restrict__ R, const float* __restrict__ bias,
             float* __restrict__ out) {
    const int b    = blockIdx.x;   // grid = 256, one batch row per block/CU
    const int d    = threadIdx.x;  // one output column per thread
    const int lane = d & 63;

    __shared__ __align__(16) float dh0[256], dh1[256];
    __shared__ __align__(16) float h10[256], h11[256];

    float rcf[256];                // R[:,d] in the unified VGPR/AGPR file
#pragma unroll
    for (int i = 0; i < 256; ++i) rcf[i] = R[(size_t)i * 256 + d];
    const float bd = bias[d];      // zeros in this problem

    dh0[d] = 0.0f;
    h10[d] = 0.0f;
    float h1 = 0.0f;
    __syncthreads();

    float* orow = out + (size_t)b * (1024 * 256);
    float u1 = orow[d];            // mm1 for t=0 (phase-1 result)

    const float* dhc = dh0; float* dhn = dh1;
    const float* h1c = h10; float* h1n = h11;

    for (int t = 0; t < 1024; ++t) {
        const float u1n = (t < 1023) ? orow[(t + 1) * 256 + d] : 0.0f;
        // RL sources for elements 128..255 (one LDS b32 each per wave)
        const float c2 = dhc[128 + lane], c3 = dhc[192 + lane];
        const float sh = (d < 64) ? 1.0f : h1c[d - 64];

        // ---- elements 0..127: ds_read_b128 broadcast, 8-deep window ----
        const float4* dh4 = reinterpret_cast<const float4*>(dhc);
        float4 w0 = dh4[0], w1 = dh4[1], w2 = dh4[2], w3 = dh4[3];
        float4 w4 = dh4[4], w5 = dh4[5], w6 = dh4[6], w7 = dh4[7];

        float acc = 0.0f;
#define GRPL(W, OFF, LD)                                                      \
        acc = fmaf(W.x, rcf[(OFF) + 0], acc);                                 \
        acc = fmaf(W.y, rcf[(OFF) + 1], acc);                                 \
        acc = fmaf(W.z, rcf[(OFF) + 2], acc);                                 \
        acc = fmaf(W.w, rcf[(OFF) + 3], acc);                                 \
        W = dh4[LD];
#define GRP(W, OFF)                                                           \
        acc = fmaf(W.x, rcf[(OFF) + 0], acc);                                 \
        acc = fmaf(W.y, rcf[(OFF) + 1], acc);                                 \
        acc = fmaf(W.z, rcf[(OFF) + 2], acc);                                 \
        acc = fmaf(W.w, rcf[(OFF) + 3], acc);
        GRPL(w0,   0,  8) GRPL(w1,   4,  9) GRPL(w2,   8, 10) GRPL(w3,  12, 11)
        GRPL(w4,  16, 12) GRPL(w5,  20, 13) GRPL(w6,  24, 14) GRPL(w7,  28, 15)
        GRPL(w0,  32, 16) GRPL(w1,  36, 17) GRPL(w2,  40, 18) GRPL(w3,  44, 19)
        GRPL(w4,  48, 20) GRPL(w5,  52, 21) GRPL(w6,  56, 22) GRPL(w7,  60, 23)
        GRPL(w0,  64, 24) GRPL(w1,  68, 25) GRPL(w2,  72, 26) GRPL(w3,  76, 27)
        GRPL(w4,  80, 28) GRPL(w5,  84, 29) GRPL(w6,  88, 30) GRPL(w7,  92, 31)
        GRP (w0,  96)     GRP (w1, 100)     GRP (w2, 104)     GRP (w3, 108)
        GRP (w4, 112)     GRP (w5, 116)     GRP (w6, 120)     GRP (w7, 124)
#undef GRPL
#undef GRP

        // ---- elements 128..255: readlane groups of 8 (r21-proven) ----
#define CHUNK(C, OFF)                                                         \
        _Pragma("unroll")                                                     \
        for (int g = 0; g < 8; ++g) {                                         \
            const int i0 = g * 8;                                             \
            const float m0 = rdlane(C, i0 + 0);                               \
            const float m1 = rdlane(C, i0 + 1);                               \
            const float m2 = rdlane(C, i0 + 2);                               \
            const float m3 = rdlane(C, i0 + 3);                               \
            const float m4 = rdlane(C, i0 + 4);                               \
            const float m5 = rdlane(C, i0 + 5);                               \
            const float m6 = rdlane(C, i0 + 6);                               \
            const float m7 = rdlane(C, i0 + 7);                               \
            acc = fmaf(m0, rcf[(OFF) + i0 + 0], acc);                         \
            acc = fmaf(m1, rcf[(OFF) + i0 + 1], acc);                         \
            acc = fmaf(m2, rcf[(OFF) + i0 + 2], acc);                         \
            acc = fmaf(m3, rcf[(OFF) + i0 + 3], acc);                         \
            acc = fmaf(m4, rcf[(OFF) + i0 + 4], acc);                         \
            acc = fmaf(m5, rcf[(OFF) + i0 + 5], acc);                         \
            acc = fmaf(m6, rcf[(OFF) + i0 + 6], acc);                         \
            acc = fmaf(m7, rcf[(OFF) + i0 + 7], acc);                         \
        }
        CHUNK(c2, 128)
        CHUNK(c3, 192)
#undef CHUNK

        const float u  = (u1 + acc) + bd;     // (mm1 + mm2) + bias
        const float z  = fmaf(sh, u, h1);
        const float hn = xla_tanh(z);

        orow[t * 256 + d] = hn;               // fire-and-forget store

        dhn[d] = hn - h1;                     // publish into the other buffer
        h1n[d] = hn;
        h1 = hn; u1 = u1n;

        const float* tp = dhc; dhc = dhn; dhn = (float*)tp;
        tp = h1c; h1c = h1n; h1n = (float*)tp;
        __syncthreads();                      // single barrier per step
    }
}

extern "C" void kernel_launch(void* const* d_in, const int* in_sizes, int n_in,
                              void* d_out, int out_size, void* d_ws, size_t ws_size,
                              hipStream_t stream) {
    // Size-based mapping (element counts); fallback to dict order.
    const float* x = nullptr; const float* K = nullptr;
    const float* R = nullptr; const float* bias = nullptr;
    for (int i = 0; i < n_in; ++i) {
        switch (in_sizes[i]) {
            case 33554432: x    = (const float*)d_in[i]; break;
            case 32768:    K    = (const float*)d_in[i]; break;
            case 65536:    R    = (const float*)d_in[i]; break;
            case 256:      bias = (const float*)d_in[i]; break;
            default: break;
        }
    }
    if (!x || !K || !R || !bias) {
        x    = (const float*)d_in[0];
        K    = (const float*)d_in[1];
        R    = (const float*)d_in[2];
        bias = (const float*)d_in[3];
    }
    float* out = (float*)d_out;

    lrs_mm1<<<1024, 256, 0, stream>>>(x, K, out);
    lrs_rec<<<256, 256, 0, stream>>>(R, bias, out);
}